// Round 8
// baseline (383.466 us; speedup 1.0000x reference)
//
#include <hip/hip_runtime.h>
#include <hip/hip_bf16.h>
#include <hip/hip_fp16.h>

typedef _Float16 f16;
typedef _Float16 f16x8 __attribute__((ext_vector_type(8)));
typedef _Float16 f16x4 __attribute__((ext_vector_type(4)));
typedef _Float16 f16x2 __attribute__((ext_vector_type(2)));
typedef float f32x4 __attribute__((ext_vector_type(4)));

#define D_MODEL 768
#define S_CTX   4096
#define NBATCH  2
#define M_TOK   (NBATCH * S_CTX)   // 8192
#define N3      (3 * D_MODEL)      // 2304

// ---------------------------------------------------------------- utilities
__device__ __forceinline__ void gload_lds16(const void* g, void* l) {
  __builtin_amdgcn_global_load_lds(
      (__attribute__((address_space(1))) unsigned int*)g,
      (__attribute__((address_space(3))) unsigned int*)l, 16, 0, 0);
}

// ---------------------------------------------------------------- fp32->fp16
__global__ __launch_bounds__(256) void cvt_f32_f16(const float* __restrict__ s,
                                                   f16* __restrict__ d, int n4) {
  int i = blockIdx.x * 256 + threadIdx.x;
  if (i >= n4) return;
  f32x4 v = ((const f32x4*)s)[i];
  f16x4 h;
  h[0] = (f16)v[0]; h[1] = (f16)v[1]; h[2] = (f16)v[2]; h[3] = (f16)v[3];
  ((f16x4*)d)[i] = h;
}

// ---------------------------------------------------------------- projection
__global__ __launch_bounds__(256, 2) void proj_gemm(
    const f16* __restrict__ A, const f16* __restrict__ B,
    f16* __restrict__ qh, f16* __restrict__ kh, f16* __restrict__ vth) {
  __shared__ f16 As[128 * 32];
  __shared__ f16 Bs[128 * 32];

  const int tid  = threadIdx.x;
  const int w    = tid >> 6, lane = tid & 63;
  const int wr   = w >> 1,   wc   = w & 1;
  const int bm0  = blockIdx.x * 128, bn0 = blockIdx.y * 128;
  const int srow = lane >> 2;
  const int scol = (lane & 3) * 8;

  f32x4 acc[4][4] = {};

  const f16* gA = A + (size_t)bm0 * 768;
  const f16* gB = B + (size_t)bn0 * 768;

  for (int kt = 0; kt < 24; ++kt) {
    __syncthreads();
    const int k0 = kt * 32 + scol;
#pragma unroll
    for (int cc = 0; cc < 2; ++cc) {
      int c = w + cc * 4;
      gload_lds16(gA + (size_t)(c * 16 + srow) * 768 + k0, (char*)As + c * 1024);
      gload_lds16(gB + (size_t)(c * 16 + srow) * 768 + k0, (char*)Bs + c * 1024);
    }
    __syncthreads();

    const int fr = lane & 15, fk = (lane >> 4) * 8;
    f16x8 af[4], bf[4];
#pragma unroll
    for (int i = 0; i < 4; ++i)
      af[i] = *(const f16x8*)(As + (wr * 64 + i * 16 + fr) * 32 + fk);
#pragma unroll
    for (int j = 0; j < 4; ++j)
      bf[j] = *(const f16x8*)(Bs + (wc * 64 + j * 16 + fr) * 32 + fk);
#pragma unroll
    for (int i = 0; i < 4; ++i)
#pragma unroll
      for (int j = 0; j < 4; ++j)
        acc[i][j] = __builtin_amdgcn_mfma_f32_16x16x32_f16(af[i], bf[j], acc[i][j], 0, 0, 0);
  }

  const int fr = lane & 15, fq = lane >> 4;
#pragma unroll
  for (int i = 0; i < 4; ++i) {
#pragma unroll
    for (int j = 0; j < 4; ++j) {
      int gn      = bn0 + wc * 64 + j * 16 + fr;
      int gm_base = bm0 + wr * 64 + i * 16 + fq * 4;
      if (gn < 1536) {
        f16* dst = (gn < 768) ? qh : kh;
        int  col = (gn < 768) ? gn : gn - 768;
#pragma unroll
        for (int r = 0; r < 4; ++r)
          dst[(size_t)(gm_base + r) * 768 + col] = (f16)acc[i][j][r];
      } else {
        int d = gn - 1536;
        int bb = gm_base >> 12, s = gm_base & 4095;
        f16x4 h;
        h[0] = (f16)acc[i][j][0]; h[1] = (f16)acc[i][j][1];
        h[2] = (f16)acc[i][j][2]; h[3] = (f16)acc[i][j][3];
        *(f16x4*)(vth + ((size_t)bb * 768 + d) * 4096 + s) = h;
      }
    }
  }
}

// ---------------------------------------------------------------- attention
// 512 thr (8 waves), LDS 68.9K -> 2 WGs/CU co-resident. KVSTEP=32.
// NO K/V LDS staging: wave (ki=wv&1, dh4=wv>>1) reads its K slice
// (rows ki*16+fr, D-slice dh4*192) straight from L2 into regs, reused for
// BOTH q-row groups (qi=0,1); V read at PV. Only Q (staged once, swizzled),
// S [4][32][34] f32 (dh4 partials), Ps, m/l/f in LDS. 2 barriers/step,
// no waitcnt asm (compiler emits exact data-dep waits); 16-wave TLP hides
// L2 latency. Pairing for consecutive co-location: u=2j heavy qb=127-(j>>2),
// u=2j+1 light qb=(j>>2) -> per-CU sum ~65 steps.
#define SM_Q    0        // 49152: f16 [32][768] swizzled
#define SM_SS   49152    // 17408: f32 [4][32][34]
#define SM_PS   66560    // 2048:  f16 [32][64B] swizzled
#define SM_M    68608
#define SM_L    68736
#define SM_F    68864
#define SM_SZ   68992

__global__ __launch_bounds__(512, 2) void attn_part(
    const f16* __restrict__ qg, const f16* __restrict__ kg,
    const f16* __restrict__ vt, f16* __restrict__ p0,
    float* __restrict__ p1, float* __restrict__ ml) {
  extern __shared__ __align__(16) char smem[];
  char*  Qs = smem + SM_Q;
  char*  Ps = smem + SM_PS;
  float* mS = (float*)(smem + SM_M);
  float* lS = (float*)(smem + SM_L);
  float* fS = (float*)(smem + SM_F);

  const int tid  = threadIdx.x;
  const int wv   = tid >> 6, lane = tid & 63;
  const int fr   = lane & 15, fq = lane >> 4;
  const int ki   = wv & 1, dh4 = wv >> 1;

  // consecutive-pair balanced mapping: (2j,2j+1) co-locate on one CU.
  const int u = blockIdx.x;
  const int j = u >> 1;
  const int qb = (u & 1) ? (j >> 2) : (127 - (j >> 2));
  const int b  = (j >> 1) & 1;
  const int c  = j & 1;
  const int q0 = qb * 32;
  const int n  = (q0 >> 5) + 1;       // KV steps of 32
  const int n0 = (n + 1) >> 1;
  const int ts = c ? n0 : 0;
  const int te = c ? n : n0;

  const f16* kb_ = kg + (size_t)b * 4096 * 768;
  const f16* vb_ = vt + (size_t)b * 768 * 4096;
  const f16* vp0 = vb_ + (size_t)(wv * 96 + fr) * 4096 + fq * 8;

  // ---- stage Q once (pre-swizzled source -> linear LDS; read with XOR)
  {
    const char* qsrc = (const char*)(qg + ((size_t)b * 4096 + q0) * 768);
#pragma unroll
    for (int i = 0; i < 6; ++i) {
      int lin = wv * 6144 + i * 1024 + lane * 16;
      int row = lin / 1536, cb = lin - row * 1536;
      gload_lds16(qsrc + (size_t)row * 1536 + (cb ^ ((row & 7) << 4)), Qs + lin);
    }
  }
  if (tid < 32) { mS[tid] = -1e30f; lS[tid] = 0.f; }
  asm volatile("s_waitcnt vmcnt(0)" ::: "memory");
  __builtin_amdgcn_s_barrier();

  f32x4 acc[2][6] = {};

  for (int t = ts; t < te; ++t) {
    const int kv0 = t * 32;

    // ---- QK^T: K slice direct from L2 (once per WG), both qi reuse kf
    {
      const f16* kp = kb_ + (size_t)(kv0 + ki * 16 + fr) * 768 + dh4 * 192 + fq * 8;
      f32x4 s0v = {}, s1v = {};
      __builtin_amdgcn_s_setprio(1);
#pragma unroll
      for (int kk = 0; kk < 6; ++kk) {
        f16x8 kf = *(const f16x8*)(kp + kk * 32);
        int off = (dh4 * 192 + kk * 32 + fq * 8) * 2;
        int r0 = fr, r1 = 16 + fr;
        f16x8 qa = *(const f16x8*)(Qs + ((r0 * 1536 + off) ^ ((r0 & 7) << 4)));
        f16x8 qbf = *(const f16x8*)(Qs + ((r1 * 1536 + off) ^ ((r1 & 7) << 4)));
        s0v = __builtin_amdgcn_mfma_f32_16x16x32_f16(qa,  kf, s0v, 0, 0, 0);
        s1v = __builtin_amdgcn_mfma_f32_16x16x32_f16(qbf, kf, s1v, 0, 0, 0);
      }
      __builtin_amdgcn_s_setprio(0);
      float* SL = (float*)(smem + SM_SS) + dh4 * 1088;
      const int colk = ki * 16 + fr;
#pragma unroll
      for (int r = 0; r < 4; ++r) {
        SL[(fq * 4 + r) * 34 + colk]      = s0v[r];
        SL[(16 + fq * 4 + r) * 34 + colk] = s1v[r];
      }
    }
    asm volatile("s_waitcnt lgkmcnt(0)" ::: "memory");
    __builtin_amdgcn_s_barrier();                       // (A) S complete

    // ---- online softmax: row = tid>>4, 2 cols/thread, sum 4 dh4 layers
    {
      const int row = tid >> 4, sub = tid & 15;
      const int c0 = sub * 2;
      const float* Sb = (const float*)(smem + SM_SS) + row * 34 + c0;
      float a0 = Sb[0] + Sb[1088] + Sb[2176] + Sb[3264];
      float a1 = Sb[1] + Sb[1089] + Sb[2177] + Sb[3265];
      const int grow = q0 + row;
      if (kv0 + c0     > grow) a0 = -1e30f;
      if (kv0 + c0 + 1 > grow) a1 = -1e30f;
      float mx = fmaxf(a0, a1);
      mx = fmaxf(mx, __shfl_xor(mx, 1));
      mx = fmaxf(mx, __shfl_xor(mx, 2));
      mx = fmaxf(mx, __shfl_xor(mx, 4));
      mx = fmaxf(mx, __shfl_xor(mx, 8));
      float mo = mS[row];
      float mn = fmaxf(mo, mx);
      float p0v = __expf(a0 - mn), p1v = __expf(a1 - mn);
      float sum = p0v + p1v;
      sum += __shfl_xor(sum, 1);
      sum += __shfl_xor(sum, 2);
      sum += __shfl_xor(sum, 4);
      sum += __shfl_xor(sum, 8);
      if (sub == 0) {
        float f = __expf(mo - mn);
        mS[row] = mn; fS[row] = f; lS[row] = lS[row] * f + sum;
      }
      f16x2 ph; ph[0] = (f16)p0v; ph[1] = (f16)p1v;
      int by = row * 64 + sub * 4;
      *(f16x2*)(Ps + (by ^ (((row >> 1) & 3) << 4))) = ph;
    }
    asm volatile("s_waitcnt lgkmcnt(0)" ::: "memory");
    __builtin_amdgcn_s_barrier();                       // (B) P, m/l/f complete

    // ---- rescale + PV (V direct from L2; compiler waits on data deps)
    {
      f32x4 f0 = *(const f32x4*)(fS + fq * 4);
      f32x4 f1 = *(const f32x4*)(fS + 16 + fq * 4);
#pragma unroll
      for (int ct = 0; ct < 6; ++ct)
#pragma unroll
        for (int r = 0; r < 4; ++r) {
          acc[0][ct][r] *= f0[r];
          acc[1][ct][r] *= f1[r];
        }
      f16x8 vreg[6];
      {
        const f16* vp = vp0 + kv0;
#pragma unroll
        for (int ct = 0; ct < 6; ++ct)
          vreg[ct] = *(const f16x8*)(vp + (size_t)ct * 16 * 4096);
      }
      int byA0 = (fr * 64 + fq * 16) ^ (((fr >> 1) & 3) << 4);
      int rb = 16 + fr;
      int byA1 = (rb * 64 + fq * 16) ^ (((rb >> 1) & 3) << 4);
      f16x8 pa0 = *(const f16x8*)(Ps + byA0);
      f16x8 pa1 = *(const f16x8*)(Ps + byA1);
      __builtin_amdgcn_s_setprio(1);
#pragma unroll
      for (int ct = 0; ct < 6; ++ct) {
        acc[0][ct] = __builtin_amdgcn_mfma_f32_16x16x32_f16(pa0, vreg[ct], acc[0][ct], 0, 0, 0);
        acc[1][ct] = __builtin_amdgcn_mfma_f32_16x16x32_f16(pa1, vreg[ct], acc[1][ct], 0, 0, 0);
      }
      __builtin_amdgcn_s_setprio(0);
    }
    // no end-of-step barrier needed: next S-writes race-free past (B),
    // next Ps/fS writes gated by next (A).
  }

  // ---- epilogue: unnormalized partial + (m,l)
  const size_t obase = (size_t)b * 4096 + q0;
  if (c == 0) {
#pragma unroll
    for (int ct = 0; ct < 6; ++ct) {
      int d = wv * 96 + ct * 16 + fr;
#pragma unroll
      for (int r = 0; r < 4; ++r) {
        p0[(obase + fq * 4 + r) * 768 + d]      = (f16)acc[0][ct][r];
        p0[(obase + 16 + fq * 4 + r) * 768 + d] = (f16)acc[1][ct][r];
      }
    }
  } else {
#pragma unroll
    for (int ct = 0; ct < 6; ++ct) {
      int d = wv * 96 + ct * 16 + fr;
#pragma unroll
      for (int r = 0; r < 4; ++r) {
        p1[(obase + fq * 4 + r) * 768 + d]      = acc[0][ct][r];
        p1[(obase + 16 + fq * 4 + r) * 768 + d] = acc[1][ct][r];
      }
    }
  }
  if (tid < 32) {
    float* mlp = ml + ((size_t)(c * 2 + b) * 4096 + q0 + tid) * 2;
    mlp[0] = mS[tid];
    mlp[1] = lS[tid];
  }
}

// ---------------------------------------------------------------- combine
__global__ __launch_bounds__(256) void attn_combine(
    const float* __restrict__ x, const f16* __restrict__ p0,
    const float* __restrict__ ml, float* __restrict__ out) {
  int i = blockIdx.x * 256 + threadIdx.x;
  int row = i / 192;
  int b = row >> 12, s = row & 4095;
  const float* m0p = ml + ((size_t)b * 4096 + s) * 2;
  const float* m1p = ml + ((size_t)(2 + b) * 4096 + s) * 2;
  float m0 = m0p[0], l0 = m0p[1];
  float m1 = m1p[0], l1 = m1p[1];
  float m  = fmaxf(m0, m1);
  float f0 = __expf(m0 - m), f1 = __expf(m1 - m);
  float inv = 1.f / (l0 * f0 + l1 * f1);
  f32x4 a1 = ((const f32x4*)out)[i];
  f16x4 a0 = ((const f16x4*)p0)[i];
  f32x4 xv = ((const f32x4*)x)[i];
  f32x4 o;
#pragma unroll
  for (int r = 0; r < 4; ++r)
    o[r] = xv[r] + ((float)a0[r] * f0 + a1[r] * f1) * inv;
  ((f32x4*)out)[i] = o;
}

// ---------------------------------------------------------------- launch
extern "C" void kernel_launch(void* const* d_in, const int* in_sizes, int n_in,
                              void* d_out, int out_size, void* d_ws, size_t ws_size,
                              hipStream_t stream) {
  const float* x  = (const float*)d_in[0];
  const float* Wp = (const float*)d_in[1];
  float* out = (float*)d_out;

  char* ws = (char*)d_ws;
  f16* x_h  = (f16*)(ws);                    // reused as p0 after proj
  f16* w_h  = (f16*)(ws + 12582912);         // reused as ml after proj
  f16* q_h  = (f16*)(ws + 16121856);
  f16* k_h  = (f16*)(ws + 28704768);
  f16* vt_h = (f16*)(ws + 41287680);

  f16*   p0 = x_h;
  float* ml = (float*)w_h;

  hipFuncSetAttribute(reinterpret_cast<const void*>(attn_part),
                      hipFuncAttributeMaxDynamicSharedMemorySize, SM_SZ);

  cvt_f32_f16<<<(M_TOK * D_MODEL) / 1024, 256, 0, stream>>>(x, x_h, (M_TOK * D_MODEL) / 4);
  cvt_f32_f16<<<(N3 * D_MODEL) / 1024, 256, 0, stream>>>(Wp, w_h, (N3 * D_MODEL) / 4);
  proj_gemm<<<dim3(64, 18), 256, 0, stream>>>(x_h, w_h, q_h, k_h, vt_h);
  attn_part<<<512, 512, SM_SZ, stream>>>(q_h, k_h, vt_h, p0, out, ml);
  attn_combine<<<(M_TOK * D_MODEL) / 1024, 256, 0, stream>>>(x, p0, ml, out);
}

// Round 10
// 281.232 us; speedup vs baseline: 1.3635x; 1.3635x over previous
//
#include <hip/hip_runtime.h>
#include <hip/hip_bf16.h>
#include <hip/hip_fp16.h>

typedef _Float16 f16;
typedef _Float16 f16x8 __attribute__((ext_vector_type(8)));
typedef _Float16 f16x4 __attribute__((ext_vector_type(4)));
typedef _Float16 f16x2 __attribute__((ext_vector_type(2)));
typedef float f32x4 __attribute__((ext_vector_type(4)));

#define D_MODEL 768
#define S_CTX   4096
#define NBATCH  2
#define M_TOK   (NBATCH * S_CTX)   // 8192
#define N3      (3 * D_MODEL)      // 2304

// ---------------------------------------------------------------- utilities
__device__ __forceinline__ void gload_lds16(const void* g, void* l) {
  __builtin_amdgcn_global_load_lds(
      (__attribute__((address_space(1))) unsigned int*)g,
      (__attribute__((address_space(3))) unsigned int*)l, 16, 0, 0);
}

// ---------------------------------------------------------------- fp32->fp16
__global__ __launch_bounds__(256) void cvt_f32_f16(const float* __restrict__ s,
                                                   f16* __restrict__ d, int n4) {
  int i = blockIdx.x * 256 + threadIdx.x;
  if (i >= n4) return;
  f32x4 v = ((const f32x4*)s)[i];
  f16x4 h;
  h[0] = (f16)v[0]; h[1] = (f16)v[1]; h[2] = (f16)v[2]; h[3] = (f16)v[3];
  ((f16x4*)d)[i] = h;
}

// ---------------------------------------------------------------- projection
__global__ __launch_bounds__(256, 2) void proj_gemm(
    const f16* __restrict__ A, const f16* __restrict__ B,
    f16* __restrict__ qh, f16* __restrict__ kh, f16* __restrict__ vth) {
  __shared__ f16 As[128 * 32];
  __shared__ f16 Bs[128 * 32];

  const int tid  = threadIdx.x;
  const int w    = tid >> 6, lane = tid & 63;
  const int wr   = w >> 1,   wc   = w & 1;
  const int bm0  = blockIdx.x * 128, bn0 = blockIdx.y * 128;
  const int srow = lane >> 2;
  const int scol = (lane & 3) * 8;

  f32x4 acc[4][4] = {};

  const f16* gA = A + (size_t)bm0 * 768;
  const f16* gB = B + (size_t)bn0 * 768;

  for (int kt = 0; kt < 24; ++kt) {
    __syncthreads();
    const int k0 = kt * 32 + scol;
#pragma unroll
    for (int cc = 0; cc < 2; ++cc) {
      int c = w + cc * 4;
      gload_lds16(gA + (size_t)(c * 16 + srow) * 768 + k0, (char*)As + c * 1024);
      gload_lds16(gB + (size_t)(c * 16 + srow) * 768 + k0, (char*)Bs + c * 1024);
    }
    __syncthreads();

    const int fr = lane & 15, fk = (lane >> 4) * 8;
    f16x8 af[4], bf[4];
#pragma unroll
    for (int i = 0; i < 4; ++i)
      af[i] = *(const f16x8*)(As + (wr * 64 + i * 16 + fr) * 32 + fk);
#pragma unroll
    for (int j = 0; j < 4; ++j)
      bf[j] = *(const f16x8*)(Bs + (wc * 64 + j * 16 + fr) * 32 + fk);
#pragma unroll
    for (int i = 0; i < 4; ++i)
#pragma unroll
      for (int j = 0; j < 4; ++j)
        acc[i][j] = __builtin_amdgcn_mfma_f32_16x16x32_f16(af[i], bf[j], acc[i][j], 0, 0, 0);
  }

  const int fr = lane & 15, fq = lane >> 4;
#pragma unroll
  for (int i = 0; i < 4; ++i) {
#pragma unroll
    for (int j = 0; j < 4; ++j) {
      int gn      = bn0 + wc * 64 + j * 16 + fr;
      int gm_base = bm0 + wr * 64 + i * 16 + fq * 4;
      if (gn < 1536) {
        f16* dst = (gn < 768) ? qh : kh;
        int  col = (gn < 768) ? gn : gn - 768;
#pragma unroll
        for (int r = 0; r < 4; ++r)
          dst[(size_t)(gm_base + r) * 768 + col] = (f16)acc[i][j][r];
      } else {
        int d = gn - 1536;
        int bb = gm_base >> 12, s = gm_base & 4095;
        f16x4 h;
        h[0] = (f16)acc[i][j][0]; h[1] = (f16)acc[i][j][1];
        h[2] = (f16)acc[i][j][2]; h[3] = (f16)acc[i][j][3];
        *(f16x4*)(vth + ((size_t)bb * 768 + d) * 4096 + s) = h;
      }
    }
  }
}

// ---------------------------------------------------------------- attention
// R3 skeleton minus one barrier and minus the V LDS round-trip.
// 512 thr (8 waves), 1 WG/CU (LDS 107K). KVSTEP=32, K double-buffered via
// global_load_lds. Per step:
//   top   : issue V(t)->regs (6), issue K[t+1]->LDS parity (t+1)&1
//           (UNCONDITIONAL tn=t+1 -> branch-free vmcnt bookkeeping; at the
//            last step tile te is garbage staged into the UNREAD parity —
//            NEVER t&1, which QK^T(t) is reading. R9's t+2 clamp hit t&1.)
//   QK^T(t) from K-LDS[t&1]; lgkm; barrier(1)
//   softmax(t); vmcnt(0)+lgkm; barrier(2)   // drains K[t+1] (and V, FIFO)
//   rescale+PV(t) from regs                  // no end-of-step barrier
#define SM_K0   0
#define SM_K1   49152
#define SM_SS   98304    // float [2 dh][32][34]
#define SM_PS   107008   // f16 [32][64B] swizzled
#define SM_M    109056
#define SM_L    109184
#define SM_F    109312
#define SM_SZ   109440

__global__ __launch_bounds__(512, 2) void attn_part(
    const f16* __restrict__ qg, const f16* __restrict__ kg,
    const f16* __restrict__ vt, f16* __restrict__ p0,
    float* __restrict__ p1, float* __restrict__ ml) {
  extern __shared__ __align__(16) char smem[];
  float* Ss0 = (float*)(smem + SM_SS);
  float* Ss1 = Ss0 + 32 * 34;
  char*  Ps  = smem + SM_PS;
  float* mS  = (float*)(smem + SM_M);
  float* lS  = (float*)(smem + SM_L);
  float* fS  = (float*)(smem + SM_F);

  const int tid  = threadIdx.x;
  const int wv   = tid >> 6, lane = tid & 63;
  const int fr   = lane & 15, fq = lane >> 4;
  const int qi   = wv >> 2, ki = (wv >> 1) & 1, dh = wv & 1;

  // R3-proven dynamic schedule: round 1 qb 127..64 desc, round 2 qb 63..0 desc
  const int u = blockIdx.x;
  int vv = (u < 256) ? u : (u - 256);
  const int qb = ((u < 256) ? 127 : 63) - (vv >> 2);
  const int b  = (vv >> 1) & 1;
  const int c  = vv & 1;
  const int q0 = qb * 32;
  const int n  = (q0 >> 5) + 1;       // KV steps of 32 for this q-block
  const int n0 = (n + 1) >> 1;
  const int ts = c ? n0 : 0;
  const int te = c ? n : n0;

  const char* kbase = (const char*)(kg + (size_t)b * 4096 * 768);
  const f16*  vbase = vt + (size_t)b * 768 * 4096;
  const f16*  vp0   = vbase + (size_t)(wv * 96 + fr) * 4096 + fq * 8;

  // ---- Q rows for this wave's QK^T tile -> registers (48 VGPR)
  f16x8 qreg[12];
  {
    const f16* qp = qg + ((size_t)b * 4096 + q0 + qi * 16 + fr) * 768 + dh * 384 + fq * 8;
#pragma unroll
    for (int kk = 0; kk < 12; ++kk) qreg[kk] = *(const f16x8*)(qp + kk * 32);
  }

  if (tid < 32) { mS[tid] = -1e30f; lS[tid] = 0.f; }

  f32x4 acc[2][6] = {};

  auto stageK = [&](int t) {          // stage K tile t into dbuf parity t&1
    const char* kb = kbase + (size_t)(t * 32) * 1536;
    char* dst = smem + ((t & 1) ? SM_K1 : SM_K0);
#pragma unroll
    for (int i = 0; i < 6; ++i) {
      int lin = wv * 6144 + i * 1024 + lane * 16;
      int row = lin / 1536, cb = lin - row * 1536;
      gload_lds16(kb + (size_t)row * 1536 + (cb ^ ((row & 7) << 4)),
                  dst + wv * 6144 + i * 1024);
    }
  };

  // ---- prologue: stage K[ts]
  stageK(ts < te ? ts : 0);
  asm volatile("s_waitcnt vmcnt(0)" ::: "memory");
  __builtin_amdgcn_s_barrier();

  for (int t = ts; t < te; ++t) {
    const int kv0 = t * 32;
    const int tn  = t + 1;   // unconditional: parity (t+1)&1, never t&1

    // ---- V(t) -> registers (issued first; FIFO => drained by bar(2) wait)
    f16x8 vreg[6];
    {
      const f16* vp = vp0 + kv0;
#pragma unroll
      for (int ct = 0; ct < 6; ++ct)
        vreg[ct] = *(const f16x8*)(vp + (size_t)ct * 16 * 4096);
    }
    // ---- issue K[t+1] -> LDS other parity (unconditional, branch-free)
    stageK(tn);

    // ---- QK^T: 12 MFMA over this wave's D-half
    {
      const char* kbuf = smem + ((t & 1) ? SM_K1 : SM_K0);
      f32x4 sc = {};
      const int krow = ki * 16 + fr;
      const int kswz = (krow & 7) << 4;
      __builtin_amdgcn_s_setprio(1);
#pragma unroll
      for (int kk = 0; kk < 12; ++kk) {
        int by = krow * 1536 + dh * 768 + kk * 64 + fq * 16;
        f16x8 kf = *(const f16x8*)(kbuf + (by ^ kswz));
        sc = __builtin_amdgcn_mfma_f32_16x16x32_f16(qreg[kk], kf, sc, 0, 0, 0);
      }
      __builtin_amdgcn_s_setprio(0);
      float* sdst = (dh ? Ss1 : Ss0) + (qi * 16 + fq * 4) * 34 + ki * 16 + fr;
#pragma unroll
      for (int r = 0; r < 4; ++r) sdst[r * 34] = sc[r];
    }
    asm volatile("s_waitcnt lgkmcnt(0)" ::: "memory");
    __builtin_amdgcn_s_barrier();                       // (1) S complete

    // ---- online softmax: row = tid>>4, 2 cols per thread
    {
      const int row = tid >> 4, sub = tid & 15;
      const int c0 = sub * 2;
      float a0 = Ss0[row * 34 + c0]     + Ss1[row * 34 + c0];
      float a1 = Ss0[row * 34 + c0 + 1] + Ss1[row * 34 + c0 + 1];
      const int grow = q0 + row;
      if (kv0 + c0     > grow) a0 = -1e30f;
      if (kv0 + c0 + 1 > grow) a1 = -1e30f;
      float mx = fmaxf(a0, a1);
      mx = fmaxf(mx, __shfl_xor(mx, 1));
      mx = fmaxf(mx, __shfl_xor(mx, 2));
      mx = fmaxf(mx, __shfl_xor(mx, 4));
      mx = fmaxf(mx, __shfl_xor(mx, 8));
      float mo = mS[row];
      float mn = fmaxf(mo, mx);
      float p0v = __expf(a0 - mn), p1v = __expf(a1 - mn);
      float sum = p0v + p1v;
      sum += __shfl_xor(sum, 1);
      sum += __shfl_xor(sum, 2);
      sum += __shfl_xor(sum, 4);
      sum += __shfl_xor(sum, 8);
      if (sub == 0) {
        float f = __expf(mo - mn);
        mS[row] = mn; fS[row] = f; lS[row] = lS[row] * f + sum;
      }
      f16x2 ph; ph[0] = (f16)p0v; ph[1] = (f16)p1v;
      int by = row * 64 + sub * 4;
      *(f16x2*)(Ps + (by ^ (((row >> 1) & 3) << 4))) = ph;
    }
    // drain K[t+1] (and V, FIFO) + P/state; single merged sync point
    asm volatile("s_waitcnt vmcnt(0) lgkmcnt(0)" ::: "memory");
    __builtin_amdgcn_s_barrier();                       // (2) P + K[t+1] ready

    // ---- rescale + PV (V in regs; P from LDS)
    {
      f32x4 f0 = *(const f32x4*)(fS + fq * 4);
      f32x4 f1 = *(const f32x4*)(fS + 16 + fq * 4);
      bool nd = (f0[0] < 1.f) | (f0[1] < 1.f) | (f0[2] < 1.f) | (f0[3] < 1.f) |
                (f1[0] < 1.f) | (f1[1] < 1.f) | (f1[2] < 1.f) | (f1[3] < 1.f);
      if (__any(nd)) {
#pragma unroll
        for (int ct = 0; ct < 6; ++ct)
#pragma unroll
          for (int r = 0; r < 4; ++r) {
            acc[0][ct][r] *= f0[r];
            acc[1][ct][r] *= f1[r];
          }
      }
      int byA0 = (fr * 64 + fq * 16) ^ (((fr >> 1) & 3) << 4);
      int rb = 16 + fr;
      int byA1 = (rb * 64 + fq * 16) ^ (((rb >> 1) & 3) << 4);
      f16x8 pa0 = *(const f16x8*)(Ps + byA0);
      f16x8 pa1 = *(const f16x8*)(Ps + byA1);
      __builtin_amdgcn_s_setprio(1);
#pragma unroll
      for (int ct = 0; ct < 6; ++ct) {
        acc[0][ct] = __builtin_amdgcn_mfma_f32_16x16x32_f16(pa0, vreg[ct], acc[0][ct], 0, 0, 0);
        acc[1][ct] = __builtin_amdgcn_mfma_f32_16x16x32_f16(pa1, vreg[ct], acc[1][ct], 0, 0, 0);
      }
      __builtin_amdgcn_s_setprio(0);
    }
    // no end-of-step barrier: next S-writes are after bar(2); next Ps-writes
    // after next bar(1); staging targets the parity not being read.
  }

  // ---- epilogue: unnormalized partial + (m,l)
  const size_t obase = (size_t)b * 4096 + q0;
  if (c == 0) {
#pragma unroll
    for (int ct = 0; ct < 6; ++ct) {
      int d = wv * 96 + ct * 16 + fr;
#pragma unroll
      for (int r = 0; r < 4; ++r) {
        p0[(obase + fq * 4 + r) * 768 + d]      = (f16)acc[0][ct][r];
        p0[(obase + 16 + fq * 4 + r) * 768 + d] = (f16)acc[1][ct][r];
      }
    }
  } else {
#pragma unroll
    for (int ct = 0; ct < 6; ++ct) {
      int d = wv * 96 + ct * 16 + fr;
#pragma unroll
      for (int r = 0; r < 4; ++r) {
        p1[(obase + fq * 4 + r) * 768 + d]      = acc[0][ct][r];
        p1[(obase + 16 + fq * 4 + r) * 768 + d] = acc[1][ct][r];
      }
    }
  }
  if (tid < 32) {
    float* mlp = ml + ((size_t)(c * 2 + b) * 4096 + q0 + tid) * 2;
    mlp[0] = mS[tid];
    mlp[1] = lS[tid];
  }
}

// ---------------------------------------------------------------- combine
__global__ __launch_bounds__(256) void attn_combine(
    const float* __restrict__ x, const f16* __restrict__ p0,
    const float* __restrict__ ml, float* __restrict__ out) {
  int i = blockIdx.x * 256 + threadIdx.x;
  int row = i / 192;
  int b = row >> 12, s = row & 4095;
  const float* m0p = ml + ((size_t)b * 4096 + s) * 2;
  const float* m1p = ml + ((size_t)(2 + b) * 4096 + s) * 2;
  float m0 = m0p[0], l0 = m0p[1];
  float m1 = m1p[0], l1 = m1p[1];
  float m  = fmaxf(m0, m1);
  float f0 = __expf(m0 - m), f1 = __expf(m1 - m);
  float inv = 1.f / (l0 * f0 + l1 * f1);
  f32x4 a1 = ((const f32x4*)out)[i];
  f16x4 a0 = ((const f16x4*)p0)[i];
  f32x4 xv = ((const f32x4*)x)[i];
  f32x4 o;
#pragma unroll
  for (int r = 0; r < 4; ++r)
    o[r] = xv[r] + ((float)a0[r] * f0 + a1[r] * f1) * inv;
  ((f32x4*)out)[i] = o;
}

// ---------------------------------------------------------------- launch
extern "C" void kernel_launch(void* const* d_in, const int* in_sizes, int n_in,
                              void* d_out, int out_size, void* d_ws, size_t ws_size,
                              hipStream_t stream) {
  const float* x  = (const float*)d_in[0];
  const float* Wp = (const float*)d_in[1];
  float* out = (float*)d_out;

  char* ws = (char*)d_ws;
  f16* x_h  = (f16*)(ws);                    // reused as p0 after proj
  f16* w_h  = (f16*)(ws + 12582912);         // reused as ml after proj
  f16* q_h  = (f16*)(ws + 16121856);
  f16* k_h  = (f16*)(ws + 28704768);
  f16* vt_h = (f16*)(ws + 41287680);

  f16*   p0 = x_h;
  float* ml = (float*)w_h;

  hipFuncSetAttribute(reinterpret_cast<const void*>(attn_part),
                      hipFuncAttributeMaxDynamicSharedMemorySize, SM_SZ);

  cvt_f32_f16<<<(M_TOK * D_MODEL) / 1024, 256, 0, stream>>>(x, x_h, (M_TOK * D_MODEL) / 4);
  cvt_f32_f16<<<(N3 * D_MODEL) / 1024, 256, 0, stream>>>(Wp, w_h, (N3 * D_MODEL) / 4);
  proj_gemm<<<dim3(64, 18), 256, 0, stream>>>(x_h, w_h, q_h, k_h, vt_h);
  attn_part<<<512, 512, SM_SZ, stream>>>(q_h, k_h, vt_h, p0, out, ml);
  attn_combine<<<(M_TOK * D_MODEL) / 1024, 256, 0, stream>>>(x, p0, ml, out);
}